// Round 1
// baseline (776.643 us; speedup 1.0000x reference)
//
#include <hip/hip_runtime.h>
#include <cstdint>
#include <cstddef>

#define Hh 18
#define H3 54
#define Tt 1024
#define CHUNK 16
#define NCH (Tt / CHUNK)

// sigmoid(u) = 1/(1+e^-u); tanh(u) = 1 - 2/(1+e^{2u})
__global__ __launch_bounds__(64) void rnn_fused(
    const float* __restrict__ x,
    const float* __restrict__ gWih, const float* __restrict__ gWhh,
    const float* __restrict__ gbih, const float* __restrict__ gbhh,
    const float* __restrict__ lWih, const float* __restrict__ lWhh,
    const float* __restrict__ lbih, const float* __restrict__ lbhh,
    const float* __restrict__ fcW, const float* __restrict__ fcb,
    float* __restrict__ out)
{
    const int lane = threadIdx.x;
    const int b    = blockIdx.x;

    __shared__ __align__(16) float xs[2][CHUNK * Hh];
    __shared__ __align__(16) float hg[Hh];
    __shared__ __align__(16) float hl[Hh];

    // ---- per-lane weights in registers ----
    // GRU: lane g < 54 owns gate row g (r:0..17, z:18..35, n:36..53)
    float wgi[Hh], wgh[Hh], bgi, bgh;
    {
        const bool v = (lane < H3);
        const int  r = v ? lane : 0;
        #pragma unroll
        for (int k = 0; k < Hh; k++) {
            wgi[k] = v ? gWih[r * Hh + k] : 0.f;
            wgh[k] = v ? gWhh[r * Hh + k] : 0.f;
        }
        bgi = v ? gbih[r] : 0.f;
        bgh = v ? gbhh[r] : 0.f;
    }
    // LSTM primary: lane owns gate row `lane` (i:0..17, f:18..35, g:36..53, o:54..71)
    float wli[Hh], whl[Hh], bli, bhl;
    #pragma unroll
    for (int k = 0; k < Hh; k++) { wli[k] = lWih[lane * Hh + k]; whl[k] = lWhh[lane * Hh + k]; }
    bli = lbih[lane]; bhl = lbhh[lane];
    // LSTM secondary: lanes 0..7 own gate rows 64..71 (o-units 10..17)
    float wli2[Hh], whl2[Hh], bli2, bhl2;
    {
        const bool v = (lane < 8);
        const int  r = v ? (64 + lane) : 64;
        #pragma unroll
        for (int k = 0; k < Hh; k++) {
            wli2[k] = v ? lWih[r * Hh + k] : 0.f;
            whl2[k] = v ? lWhh[r * Hh + k] : 0.f;
        }
        bli2 = v ? lbih[r] : 0.f;
        bhl2 = v ? lbhh[r] : 0.f;
    }

    // unified activation constants for LSTM primary round: tanh on g-lanes, sigmoid else
    const bool  isg = (lane >= 36) && (lane < H3);
    const float kk  = isg ? 2.f : 1.f;
    const float Aa  = isg ? 2.f : 1.f;
    const float Bb  = isg ? -1.f : 0.f;

    const float fcw  = (lane < Hh) ? fcW[lane] : 0.f;
    const float fcbv = fcb[0];

    if (lane < Hh) { hg[lane] = 0.f; hl[lane] = 0.f; }
    float myh = 0.f, myc = 0.f;

    const float* xb   = x   + (size_t)b * (Tt * Hh);
    float*       outp = out + (size_t)b * Tt;

    // ---- preload chunk 0 of x (288 floats) ----
    float p0, p1, p2, p3, p4;
    p0 = xb[lane];       p1 = xb[lane + 64];
    p2 = xb[lane + 128]; p3 = xb[lane + 192];
    p4 = (lane < 32) ? xb[lane + 256] : 0.f;
    xs[0][lane] = p0; xs[0][lane + 64] = p1; xs[0][lane + 128] = p2; xs[0][lane + 192] = p3;
    if (lane < 32) xs[0][lane + 256] = p4;
    __syncthreads();

    float o0 = 0.f, o1 = 0.f, o2 = 0.f, o3 = 0.f;

    for (int c = 0; c < NCH; c++) {
        const int cb = c & 1;
        // issue next chunk's global loads early; consumed (ds_write) at chunk end
        if (c + 1 < NCH) {
            const float* xn = xb + (c + 1) * (CHUNK * Hh);
            p0 = xn[lane];       p1 = xn[lane + 64];
            p2 = xn[lane + 128]; p3 = xn[lane + 192];
            if (lane < 32) p4 = xn[lane + 256];
        }
        #pragma unroll 4
        for (int s = 0; s < CHUNK; s++) {
            const float* xrow = &xs[cb][s * Hh];
            // ---- GRU ----
            float xa = bgi, ha = bgh;
            #pragma unroll
            for (int k = 0; k < Hh; k++) xa += wgi[k] * xrow[k];
            #pragma unroll
            for (int k = 0; k < Hh; k++) ha += wgh[k] * hg[k];
            const float u1 = xa + ha;
            const float sg = __fdividef(1.f, 1.f + __expf(-u1));        // r,z on their lanes
            const float rv = __shfl(sg, (lane - 36) & 63, 64);          // r_j -> n-lane 36+j
            const float un = xa + rv * ha;
            const float tn = 1.f - __fdividef(2.f, 1.f + __expf(2.f * un)); // tanh, n-lanes
            const float zz = __shfl(sg, (lane + 18) & 63, 64);          // z_i -> lane i
            const float nn = __shfl(tn, (lane + 36) & 63, 64);          // n_i -> lane i
            const float hnew = nn + zz * (myh - nn);                    // (1-z)n + z h
            if (lane < Hh) { myh = hnew; hg[lane] = hnew; }
            __builtin_amdgcn_wave_barrier();

            // ---- LSTM (input = hg just written) ----
            float xl = bli, hla = bhl, xl2 = bli2, hl2 = bhl2;
            #pragma unroll
            for (int k = 0; k < Hh; k++) { const float gk = hg[k]; xl  += wli[k]  * gk; xl2 += wli2[k] * gk; }
            #pragma unroll
            for (int k = 0; k < Hh; k++) { const float hk = hl[k]; hla += whl[k]  * hk; hl2 += whl2[k] * hk; }
            const float ul = xl + hla;
            const float a3 = __fdividef(Aa, 1.f + __expf(-kk * ul)) + Bb;  // i/f/o sigmoid, g tanh
            const float u2 = xl2 + hl2;
            const float a4 = __fdividef(1.f, 1.f + __expf(-u2));           // o-units 10..17 (lanes 0..7)
            const float ff = __shfl(a3, (lane + 18) & 63, 64);
            const float gg = __shfl(a3, (lane + 36) & 63, 64);
            const float oa = __shfl(a3, (lane + 54) & 63, 64);
            const float ob = __shfl(a4, (lane - 10) & 63, 64);
            const float oo = (lane < 10) ? oa : ob;
            const float cn = ff * myc + a3 * gg;                           // a3 on lane<18 is i-gate
            if (lane < Hh) myc = cn;
            const float tc  = 1.f - __fdividef(2.f, 1.f + __expf(2.f * cn));
            const float hlv = oo * tc;
            if (lane < Hh) hl[lane] = hlv;
            __builtin_amdgcn_wave_barrier();

            // ---- FC (18 -> 1), xor-tree over first 32 lanes (lanes>=18 contribute 0) ----
            float fv = fcw * hlv;
            fv += __shfl_xor(fv, 1, 64);
            fv += __shfl_xor(fv, 2, 64);
            fv += __shfl_xor(fv, 4, 64);
            fv += __shfl_xor(fv, 8, 64);
            fv += __shfl_xor(fv, 16, 64);
            const float ov = fv + fcbv;
            const int sm = s & 3;
            if (sm == 0) o0 = ov; else if (sm == 1) o1 = ov; else if (sm == 2) o2 = ov; else o3 = ov;
            if (sm == 3 && lane == 0) {
                float4 vv; vv.x = o0; vv.y = o1; vv.z = o2; vv.w = o3;
                *reinterpret_cast<float4*>(outp + c * CHUNK + s - 3) = vv;
            }
        }
        // land prefetched x into the other buffer
        if (c + 1 < NCH) {
            const int nb = cb ^ 1;
            __builtin_amdgcn_wave_barrier();
            xs[nb][lane] = p0; xs[nb][lane + 64] = p1; xs[nb][lane + 128] = p2; xs[nb][lane + 192] = p3;
            if (lane < 32) xs[nb][lane + 256] = p4;
            __builtin_amdgcn_wave_barrier();
        }
    }
}

extern "C" void kernel_launch(void* const* d_in, const int* in_sizes, int n_in,
                              void* d_out, int out_size, void* d_ws, size_t ws_size,
                              hipStream_t stream)
{
    const float* xx   = (const float*)d_in[0];
    const float* gWih = (const float*)d_in[1];
    const float* gWhh = (const float*)d_in[2];
    const float* gbih = (const float*)d_in[3];
    const float* gbhh = (const float*)d_in[4];
    const float* lWih = (const float*)d_in[5];
    const float* lWhh = (const float*)d_in[6];
    const float* lbih = (const float*)d_in[7];
    const float* lbhh = (const float*)d_in[8];
    const float* fcW  = (const float*)d_in[9];
    const float* fcb  = (const float*)d_in[10];
    float* outp = (float*)d_out;

    dim3 grid(1024), block(64);
    hipLaunchKernelGGL(rnn_fused, grid, block, 0, stream,
                       xx, gWih, gWhh, gbih, gbhh,
                       lWih, lWhh, lbih, lbhh, fcW, fcb, outp);
}

// Round 2
// 642.236 us; speedup vs baseline: 1.2093x; 1.2093x over previous
//
#include <hip/hip_runtime.h>
#include <cstdint>
#include <cstddef>
#include <math.h>

#define Hh 18
#define Tt 1024
#define CHUNK 16
#define NCH (Tt / CHUNK)
#define XP 20          // padded LDS row (floats) so float4 loads are 16B-aligned

#define LC 1.44269504088896340736f   // log2(e)

__device__ __forceinline__ float sigm_(float u) {
    return __fdividef(1.f, 1.f + exp2f(-LC * u));
}
__device__ __forceinline__ float tanh_(float u) {
    return fmaf(-2.f, __fdividef(1.f, 1.f + exp2f((2.f * LC) * u)), 1.f);
}
// 18-float broadcast LDS row -> registers (aligned b128 reads)
__device__ __forceinline__ void ld18_(float* d, const float* s) {
    *(float4*)&d[0]  = *(const float4*)&s[0];
    *(float4*)&d[4]  = *(const float4*)&s[4];
    *(float4*)&d[8]  = *(const float4*)&s[8];
    *(float4*)&d[12] = *(const float4*)&s[12];
    d[16] = s[16]; d[17] = s[17];
}
__device__ __forceinline__ float dot18_(const float* v, const float* w, float bias) {
    float a0 = bias, a1 = 0.f;
    #pragma unroll
    for (int k = 0; k < Hh; k += 2) {
        a0 = fmaf(w[k],     v[k],     a0);
        a1 = fmaf(w[k + 1], v[k + 1], a1);
    }
    return a0 + a1;
}

__global__ __launch_bounds__(128, 2) void rnn_fused2(
    const float* __restrict__ x,
    const float* __restrict__ gWih, const float* __restrict__ gWhh,
    const float* __restrict__ gbih, const float* __restrict__ gbhh,
    const float* __restrict__ lWih, const float* __restrict__ lWhh,
    const float* __restrict__ lbih, const float* __restrict__ lbhh,
    const float* __restrict__ fcW, const float* __restrict__ fcb,
    float* __restrict__ out)
{
    const int tid  = threadIdx.x;
    const int w    = tid >> 6;     // 0: GRU + LSTM x-proj, 1: LSTM recurrence + FC
    const int lane = tid & 63;
    const int b    = blockIdx.x;

    __shared__ __align__(16) float xs[2][CHUNK * XP];  // x chunk, padded rows
    __shared__ __align__(16) float gbuf[2][XP];        // GRU h (= LSTM input), dbuf
    __shared__ __align__(16) float hlb[XP];            // LSTM h broadcast
    __shared__ __align__(16) float xlb[2][80];         // LSTM x-projection (72 gates), dbuf

    // ---- unified per-lane weight registers (loaded per wave role) ----
    float wA[Hh], wB[Hh], wE[Hh], wF[Hh];
    float b0, b1, b2 = 0.f, b3 = 0.f;
    if (w == 0) {
        const int rg = (lane < 54) ? lane : 0;           // GRU gate row (r/z/n)
        #pragma unroll
        for (int k = 0; k < Hh; k++) {
            wA[k] = gWih[rg * Hh + k];
            wB[k] = gWhh[rg * Hh + k];
            wE[k] = lWih[lane * Hh + k];                 // LSTM Wih primary row
            wF[k] = (lane < 8) ? lWih[(64 + lane) * Hh + k] : 0.f; // secondary rows 64..71
        }
        b0 = gbih[rg]; b1 = gbhh[rg];
        b2 = lbih[lane]; b3 = (lane < 8) ? lbih[64 + lane] : 0.f;
    } else {
        const int rs = (lane < 8) ? (64 + lane) : 64;
        #pragma unroll
        for (int k = 0; k < Hh; k++) {
            wA[k] = lWhh[lane * Hh + k];                 // LSTM Whh primary row
            wB[k] = lWhh[rs * Hh + k];                   // secondary
            wE[k] = 0.f; wF[k] = 0.f;
        }
        b0 = lbhh[lane]; b1 = lbhh[rs];
    }

    // shuffle source-lane indices (loop-invariant)
    const int i1 = (lane + 18) & 63;                      // z / f
    const int i2 = (lane + 36) & 63;                      // n / g
    const int i3 = (w == 0) ? ((lane - 36) & 63) : ((lane + 54) & 63); // r-src / o-src
    const int i4 = (lane - 10) & 63;                      // o secondary src

    // wave1 unified activation: tanh on g-lanes (36..53), sigmoid elsewhere
    const bool  isg = (w == 1) && (lane >= 36) && (lane < 54);
    const float kl  = isg ? (2.f * LC) : LC;
    const float Aa  = isg ? 2.f : 1.f;
    const float Bb  = isg ? -1.f : 0.f;

    const float fcw  = (w == 1 && lane < Hh) ? fcW[lane] : 0.f;
    const float fcbv = fcb[0];

    const float* xb   = x   + (size_t)b * (Tt * Hh);
    float*       outp = out + (size_t)b * Tt;

    if (w == 0 && lane < Hh) { gbuf[0][lane] = 0.f; gbuf[1][lane] = 0.f; }
    if (w == 1 && lane < Hh) { hlb[lane] = 0.f; }

    // ---- preload chunk 0 of x into padded LDS layout ----
    float p0 = 0, p1 = 0, p2 = 0, p3 = 0, p4 = 0;
    if (w == 0) {
        p0 = xb[lane]; p1 = xb[lane + 64]; p2 = xb[lane + 128]; p3 = xb[lane + 192];
        if (lane < 32) p4 = xb[lane + 256];
        int j;
        j = lane;       xs[0][(j / Hh) * XP + (j % Hh)] = p0;
        j = lane + 64;  xs[0][(j / Hh) * XP + (j % Hh)] = p1;
        j = lane + 128; xs[0][(j / Hh) * XP + (j % Hh)] = p2;
        j = lane + 192; xs[0][(j / Hh) * XP + (j % Hh)] = p3;
        if (lane < 32) { j = lane + 256; xs[0][(j / Hh) * XP + (j % Hh)] = p4; }
    }
    __syncthreads();

    float myh = 0.f, myc = 0.f;
    float o0 = 0, o1 = 0, o2 = 0, o3 = 0;

    for (int c = 0; c < NCH; c++) {
        const int cb = c & 1;
        if (w == 0 && c + 1 < NCH) {  // issue next chunk's global loads early
            const float* xn = xb + (c + 1) * (CHUNK * Hh);
            p0 = xn[lane]; p1 = xn[lane + 64]; p2 = xn[lane + 128]; p3 = xn[lane + 192];
            if (lane < 32) p4 = xn[lane + 256];
        }
        #pragma unroll 2
        for (int s = 0; s < CHUNK; s++) {
            const int it = c * CHUNK + s;
            if (w == 0) {
                // ---- GRU step it ----
                float xv[Hh], hv[Hh], gv[Hh];
                ld18_(xv, &xs[cb][s * XP]);
                ld18_(hv, gbuf[(it + 1) & 1]);            // h[it-1]
                const float xa = dot18_(xv, wA, b0);
                const float ha = dot18_(hv, wB, b1);
                const float sg = sigm_(xa + ha);          // r,z on their lanes
                const float rv = __shfl(sg, i3, 64);
                const float un = fmaf(rv, ha, xa);
                const float tn = tanh_(un);
                const float zz = __shfl(sg, i1, 64);
                const float nn = __shfl(tn, i2, 64);
                const float hnew = fmaf(zz, myh - nn, nn);
                if (lane < Hh) { myh = hnew; gbuf[it & 1][lane] = hnew; }
                __builtin_amdgcn_wave_barrier();
                // ---- LSTM x-projection for step it (feeds wave1 next iter) ----
                ld18_(gv, gbuf[it & 1]);
                const float xl  = dot18_(gv, wE, b2);
                const float xl2 = dot18_(gv, wF, b3);
                xlb[it & 1][lane] = xl;
                if (lane < 8) xlb[it & 1][64 + lane] = xl2;
            } else if (it > 0) {
                // ---- LSTM step u = it-1 ----
                const int u = it - 1;
                float hv[Hh];
                ld18_(hv, hlb);
                const float hla = dot18_(hv, wA, b0);
                const float hl2 = dot18_(hv, wB, b1);
                const float xl  = xlb[u & 1][lane];
                const float xl2 = xlb[u & 1][64 + (lane & 7)];
                const float ul  = xl + hla;
                const float a3  = fmaf(Aa, __fdividef(1.f, 1.f + exp2f(-kl * ul)), Bb);
                const float a4  = sigm_(xl2 + hl2);
                const float ff  = __shfl(a3, i1, 64);
                const float gg  = __shfl(a3, i2, 64);
                const float oa  = __shfl(a3, i3, 64);
                const float ob  = __shfl(a4, i4, 64);
                const float oo  = (lane < 10) ? oa : ob;
                const float cn  = ff * myc + a3 * gg;     // a3 on lanes<18 = i-gate
                if (lane < Hh) myc = cn;
                const float tc  = tanh_(cn);
                const float hlv = oo * tc;
                if (lane < Hh) hlb[lane] = hlv;
                __builtin_amdgcn_wave_barrier();
                // ---- FC ----
                float fv = fcw * hlv;
                fv += __shfl_xor(fv, 1, 64);
                fv += __shfl_xor(fv, 2, 64);
                fv += __shfl_xor(fv, 4, 64);
                fv += __shfl_xor(fv, 8, 64);
                fv += __shfl_xor(fv, 16, 64);
                const float ov = fv + fcbv;
                const int sm = u & 3;
                if (sm == 0) o0 = ov; else if (sm == 1) o1 = ov; else if (sm == 2) o2 = ov; else o3 = ov;
                if (sm == 3 && lane == 0) {
                    float4 vv; vv.x = o0; vv.y = o1; vv.z = o2; vv.w = o3;
                    *reinterpret_cast<float4*>(outp + u - 3) = vv;
                }
            }
            __syncthreads();
        }
        if (w == 0 && c + 1 < NCH) {  // land prefetched x into other buffer
            const int nb = cb ^ 1;
            int j;
            j = lane;       xs[nb][(j / Hh) * XP + (j % Hh)] = p0;
            j = lane + 64;  xs[nb][(j / Hh) * XP + (j % Hh)] = p1;
            j = lane + 128; xs[nb][(j / Hh) * XP + (j % Hh)] = p2;
            j = lane + 192; xs[nb][(j / Hh) * XP + (j % Hh)] = p3;
            if (lane < 32) { j = lane + 256; xs[nb][(j / Hh) * XP + (j % Hh)] = p4; }
        }
    }

    // ---- tail: LSTM step u = 1023 (wave1 only) ----
    if (w == 1) {
        const int u = Tt - 1;
        float hv[Hh];
        ld18_(hv, hlb);
        const float hla = dot18_(hv, wA, b0);
        const float hl2 = dot18_(hv, wB, b1);
        const float xl  = xlb[u & 1][lane];
        const float xl2 = xlb[u & 1][64 + (lane & 7)];
        const float ul  = xl + hla;
        const float a3  = fmaf(Aa, __fdividef(1.f, 1.f + exp2f(-kl * ul)), Bb);
        const float a4  = sigm_(xl2 + hl2);
        const float ff  = __shfl(a3, i1, 64);
        const float gg  = __shfl(a3, i2, 64);
        const float oa  = __shfl(a3, i3, 64);
        const float ob  = __shfl(a4, i4, 64);
        const float oo  = (lane < 10) ? oa : ob;
        const float cn  = ff * myc + a3 * gg;
        const float tc  = tanh_(cn);
        const float hlv = oo * tc;
        float fv = fcw * hlv;
        fv += __shfl_xor(fv, 1, 64);
        fv += __shfl_xor(fv, 2, 64);
        fv += __shfl_xor(fv, 4, 64);
        fv += __shfl_xor(fv, 8, 64);
        fv += __shfl_xor(fv, 16, 64);
        const float ov = fv + fcbv;
        o3 = ov;
        if (lane == 0) {
            float4 vv; vv.x = o0; vv.y = o1; vv.z = o2; vv.w = o3;
            *reinterpret_cast<float4*>(outp + u - 3) = vv;
        }
    }
}

extern "C" void kernel_launch(void* const* d_in, const int* in_sizes, int n_in,
                              void* d_out, int out_size, void* d_ws, size_t ws_size,
                              hipStream_t stream)
{
    const float* xx   = (const float*)d_in[0];
    const float* gWih = (const float*)d_in[1];
    const float* gWhh = (const float*)d_in[2];
    const float* gbih = (const float*)d_in[3];
    const float* gbhh = (const float*)d_in[4];
    const float* lWih = (const float*)d_in[5];
    const float* lWhh = (const float*)d_in[6];
    const float* lbih = (const float*)d_in[7];
    const float* lbhh = (const float*)d_in[8];
    const float* fcW  = (const float*)d_in[9];
    const float* fcb  = (const float*)d_in[10];
    float* outp = (float*)d_out;

    dim3 grid(1024), block(128);
    hipLaunchKernelGGL(rnn_fused2, grid, block, 0, stream,
                       xx, gWih, gWhh, gbih, gbhh,
                       lWih, lWhh, lbih, lbhh, fcW, fcb, outp);
}

// Round 3
// 523.547 us; speedup vs baseline: 1.4834x; 1.2267x over previous
//
#include <hip/hip_runtime.h>
#include <cstdint>
#include <cstddef>
#include <math.h>

#define Hh 18
#define Tt 1024
#define WSTEP 8                // steps per window
#define NW (Tt / WSTEP)        // 128 windows

#define LC 1.44269504088896340736f   // log2(e)

__device__ __forceinline__ float sigm_(float u) {
    return __fdividef(1.f, 1.f + exp2f(-LC * u));
}
__device__ __forceinline__ float tanh_(float u) {
    return fmaf(-2.f, __fdividef(1.f, 1.f + exp2f((2.f * LC) * u)), 1.f);
}
// 18-float broadcast LDS row -> registers (rows are 16B-aligned)
__device__ __forceinline__ void ld18_(float* d, const float* s) {
    *(float4*)&d[0]  = *(const float4*)&s[0];
    *(float4*)&d[4]  = *(const float4*)&s[4];
    *(float4*)&d[8]  = *(const float4*)&s[8];
    *(float4*)&d[12] = *(const float4*)&s[12];
    d[16] = s[16]; d[17] = s[17];
}
__device__ __forceinline__ float dot18_(const float* v, const float* w, float bias) {
    float a0 = bias, a1 = 0.f;
    #pragma unroll
    for (int k = 0; k < Hh; k += 2) {
        a0 = fmaf(w[k],     v[k],     a0);
        a1 = fmaf(w[k + 1], v[k + 1], a1);
    }
    return a0 + a1;
}

// roles: wave0 = GRU recurrence + LSTM x-proj; wave1 = LSTM recurrence + FC;
//        wave2 = GRU input projection (h-independent), one window ahead.
__global__ __launch_bounds__(192, 3) void rnn_fused3(
    const float* __restrict__ x,
    const float* __restrict__ gWih, const float* __restrict__ gWhh,
    const float* __restrict__ gbih, const float* __restrict__ gbhh,
    const float* __restrict__ lWih, const float* __restrict__ lWhh,
    const float* __restrict__ lbih, const float* __restrict__ lbhh,
    const float* __restrict__ fcW, const float* __restrict__ fcb,
    float* __restrict__ out)
{
    const int tid  = threadIdx.x;
    const int role = tid >> 6;
    const int lane = tid & 63;
    const int b    = blockIdx.x;

    __shared__ __align__(16) float xab[16][64];    // GRU input-proj ring (slot = t&15)
    __shared__ __align__(16) float xlb[16][80];    // LSTM input-proj ring
    __shared__ __align__(16) float xst[2][WSTEP][20]; // staged x for wave2
    __shared__ __align__(16) float gbuf[20];       // GRU h (wave0-private)
    __shared__ __align__(16) float hlb[20];        // LSTM h (wave1-private)

    // ---- per-role weight registers ----
    float wA[Hh], wB[Hh], wC[Hh];
    float b0 = 0.f, b1 = 0.f, b2 = 0.f;
    if (role == 0) {
        const int rg = (lane < 54) ? lane : 0;
        #pragma unroll
        for (int k = 0; k < Hh; k++) {
            wA[k] = gWhh[rg * Hh + k];                          // GRU Whh row
            wB[k] = lWih[lane * Hh + k];                        // LSTM Wih primary
            wC[k] = (lane < 8) ? lWih[(64 + lane) * Hh + k] : 0.f; // LSTM Wih secondary
        }
        b0 = gbhh[rg];
        b1 = lbih[lane];
        b2 = (lane < 8) ? lbih[64 + lane] : 0.f;
    } else if (role == 1) {
        const int rs = (lane < 8) ? (64 + lane) : 64;
        #pragma unroll
        for (int k = 0; k < Hh; k++) {
            wA[k] = lWhh[lane * Hh + k];                        // LSTM Whh primary
            wB[k] = lWhh[rs * Hh + k];                          // secondary
            wC[k] = 0.f;
        }
        b0 = lbhh[lane]; b1 = lbhh[rs];
    } else {
        const int rg = (lane < 54) ? lane : 0;
        #pragma unroll
        for (int k = 0; k < Hh; k++) {
            wA[k] = gWih[rg * Hh + k];                          // GRU Wih row
            wB[k] = 0.f; wC[k] = 0.f;
        }
        b0 = gbih[rg];
    }

    // shuffle source-lane indices
    const int i1 = (lane + 18) & 63;   // z / f
    const int i2 = (lane + 36) & 63;   // n / g
    const int i3 = (role == 0) ? ((lane - 36) & 63) : ((lane + 54) & 63); // r-src / o-src
    const int i4 = (lane - 10) & 63;   // o secondary src

    // wave1 unified activation: tanh on g-lanes (36..53), sigmoid elsewhere
    const bool  isg = (role == 1) && (lane >= 36) && (lane < 54);
    const float kl  = isg ? (2.f * LC) : LC;
    const float Aa  = isg ? 2.f : 1.f;
    const float Bb  = isg ? -1.f : 0.f;

    const float fcw  = (role == 1 && lane < Hh) ? fcW[lane] : 0.f;
    const float fcbv = fcb[0];

    const float* xb   = x   + (size_t)b * (Tt * Hh);
    float*       outp = out + (size_t)b * Tt;

    float myh = 0.f, myc = 0.f;
    float o0 = 0, o1 = 0, o2 = 0, o3 = 0;
    float px0 = 0.f, px1 = 0.f, px2 = 0.f;

    // ---- prologue ----
    if (role == 0 && lane < Hh) gbuf[lane] = 0.f;
    if (role == 1 && lane < Hh) hlb[lane]  = 0.f;
    if (role == 2) {
        // stage x window 0, compute xa slots 0..7
        px0 = xb[lane]; px1 = xb[64 + lane]; px2 = (lane < 16) ? xb[128 + lane] : 0.f;
        { int j = lane;      xst[0][j / Hh][j % Hh] = px0;
          j = 64 + lane;     xst[0][j / Hh][j % Hh] = px1;
          if (lane < 16) { j = 128 + lane; xst[0][j / Hh][j % Hh] = px2; } }
        #pragma unroll
        for (int j = 0; j < WSTEP; j++) {
            float xr[Hh]; ld18_(xr, &xst[0][j][0]);
            xab[j][lane] = dot18_(xr, wA, b0);
        }
        // prefetch x window 1
        const float* xw = xb + WSTEP * Hh;
        px0 = xw[lane]; px1 = xw[64 + lane]; if (lane < 16) px2 = xw[128 + lane];
    }

    for (int w = 0; w <= NW; w++) {
        __syncthreads();

        if (role == 2 && w <= NW - 2) {
            // produce xa for window W = w+1
            const int W = w + 1;
            const int xbuf = W & 1;
            { int j = lane;      xst[xbuf][j / Hh][j % Hh] = px0;
              j = 64 + lane;     xst[xbuf][j / Hh][j % Hh] = px1;
              if (lane < 16) { j = 128 + lane; xst[xbuf][j / Hh][j % Hh] = px2; } }
            if (w + 2 <= NW - 1) {  // prefetch x window w+2
                const float* xw = xb + (size_t)(w + 2) * (WSTEP * Hh);
                px0 = xw[lane]; px1 = xw[64 + lane]; if (lane < 16) px2 = xw[128 + lane];
            }
            #pragma unroll
            for (int j = 0; j < WSTEP; j++) {
                float xr[Hh]; ld18_(xr, &xst[xbuf][j][0]);
                xab[(8 * W + j) & 15][lane] = dot18_(xr, wA, b0);
            }
        }

        if (role == 0 && w <= NW - 1) {
            #pragma unroll 4
            for (int j = 0; j < WSTEP; j++) {
                const int t = 8 * w + j;
                float hv[Hh];
                ld18_(hv, gbuf);                        // h[t-1]
                const float xa = xab[t & 15][lane];     // gWih·x + bih (row = lane)
                const float ha = dot18_(hv, wA, b0);
                const float sg = sigm_(xa + ha);        // r,z on their lanes
                const float rv = __shfl(sg, i3, 64);
                const float un = fmaf(rv, ha, xa);
                const float tn = tanh_(un);
                const float zz = __shfl(sg, i1, 64);
                const float nn = __shfl(tn, i2, 64);
                const float hnew = fmaf(zz, myh - nn, nn);
                if (lane < Hh) { myh = hnew; gbuf[lane] = hnew; }
                __builtin_amdgcn_wave_barrier();
                // LSTM x-projection for step t
                float gv[Hh];
                ld18_(gv, gbuf);
                const float xl  = dot18_(gv, wB, b1);
                const float xl2 = dot18_(gv, wC, b2);
                xlb[t & 15][lane] = xl;
                if (lane < 8) xlb[t & 15][64 + lane] = xl2;
            }
        }

        if (role == 1 && w >= 1) {
            #pragma unroll 4
            for (int j = 0; j < WSTEP; j++) {
                const int u = 8 * (w - 1) + j;
                float hv[Hh];
                ld18_(hv, hlb);
                const float hla = dot18_(hv, wA, b0);
                const float hl2 = dot18_(hv, wB, b1);
                const float xl  = xlb[u & 15][lane];
                const float xl2 = xlb[u & 15][64 + (lane & 7)];
                const float ul  = xl + hla;
                const float a3  = fmaf(Aa, __fdividef(1.f, 1.f + exp2f(-kl * ul)), Bb);
                const float a4  = sigm_(xl2 + hl2);
                const float ff  = __shfl(a3, i1, 64);
                const float gg  = __shfl(a3, i2, 64);
                const float oa  = __shfl(a3, i3, 64);
                const float ob  = __shfl(a4, i4, 64);
                const float oo  = (lane < 10) ? oa : ob;
                const float cn  = ff * myc + a3 * gg;   // a3 on lanes<18 = i-gate
                if (lane < Hh) myc = cn;
                const float tc  = tanh_(cn);
                const float hlv = oo * tc;
                if (lane < Hh) hlb[lane] = hlv;
                __builtin_amdgcn_wave_barrier();
                // FC
                float fv = fcw * hlv;
                fv += __shfl_xor(fv, 1, 64);
                fv += __shfl_xor(fv, 2, 64);
                fv += __shfl_xor(fv, 4, 64);
                fv += __shfl_xor(fv, 8, 64);
                fv += __shfl_xor(fv, 16, 64);
                const float ov = fv + fcbv;
                const int sm = j & 3;
                if (sm == 0) o0 = ov; else if (sm == 1) o1 = ov; else if (sm == 2) o2 = ov; else o3 = ov;
                if (sm == 3 && lane == 0) {
                    float4 vv; vv.x = o0; vv.y = o1; vv.z = o2; vv.w = o3;
                    *reinterpret_cast<float4*>(outp + u - 3) = vv;
                }
            }
        }
    }
}

extern "C" void kernel_launch(void* const* d_in, const int* in_sizes, int n_in,
                              void* d_out, int out_size, void* d_ws, size_t ws_size,
                              hipStream_t stream)
{
    const float* xx   = (const float*)d_in[0];
    const float* gWih = (const float*)d_in[1];
    const float* gWhh = (const float*)d_in[2];
    const float* gbih = (const float*)d_in[3];
    const float* gbhh = (const float*)d_in[4];
    const float* lWih = (const float*)d_in[5];
    const float* lWhh = (const float*)d_in[6];
    const float* lbih = (const float*)d_in[7];
    const float* lbhh = (const float*)d_in[8];
    const float* fcW  = (const float*)d_in[9];
    const float* fcb  = (const float*)d_in[10];
    float* outp = (float*)d_out;

    dim3 grid(1024), block(192);
    hipLaunchKernelGGL(rnn_fused3, grid, block, 0, stream,
                       xx, gWih, gWhh, gbih, gbhh,
                       lWih, lWhh, lbih, lbhh, fcW, fcb, outp);
}